// Round 3
// baseline (155.174 us; speedup 1.0000x reference)
//
#include <hip/hip_runtime.h>
#include <hip/hip_bf16.h>
#include <math.h>

// FFM: B=32768, n=512, f=30, k=40
// inter[b] = X[b]^T W X[b],  W = 0.5*(C - diag(C)), C symmetric
// out = sigmoid(X@w1 + b + inter)
//
// R8: A-fragments hoisted to registers (32 x short8 = 128 VGPR per thread,
// read once from As instead of 4x per cb panel) -> inner loop is 2 ds_read
// + 4 MFMA per kk. BK=128 K-steps (Bs dbuf 2x32KB, 4 staging loads/thread,
// vmcnt(4) counted wait, 2 barriers/step, 16 steps). setprio around MFMA.
// build_w16: LDS-staged coalesced loads (was 64-line uncoalesced gather).

#define N_FEAT 512
#define FK 1200
#define KDIM 40
#define B_ROWS 32768
#define BM 64
#define BK2 128

typedef __attribute__((ext_vector_type(8))) short short8;
typedef __attribute__((ext_vector_type(4))) float f32x4;

__device__ __forceinline__ unsigned short bf16_rne(float f) {
    union { float f; unsigned int u; } c; c.f = f;
    unsigned int u = c.u;
    u += 0x7fffu + ((u >> 16) & 1u);
    return (unsigned short)(u >> 16);
}

__device__ __forceinline__ float bf16_to_f(unsigned short h) {
    union { unsigned int u; float f; } c;
    c.u = ((unsigned int)h) << 16;
    return c.f;
}

__device__ __forceinline__ void async_copy16(const void* g, void* l) {
    __builtin_amdgcn_global_load_lds(
        (const __attribute__((address_space(1))) void*)g,
        (__attribute__((address_space(3))) void*)l,
        16, 0, 0);
}

#define FENCE() asm volatile("" ::: "memory")

// ---------------- Kernel 1: build W16 (512x512 bf16) ----------------
// Block: i = blockIdx.y, j-tile = blockIdx.x*256. Coalesced LDS staging:
// a_lds = v[i][:][:] (whole row, 4.8KB); c_lds = v[j][fi][:] for the j-tile
// (256 rows x 40 floats, padded to 44 -> 2-way-free banks). Dot from LDS,
// identical FMA order to previous version (bit-identical W16).
__global__ __launch_bounds__(256) void build_w16(const float* __restrict__ v,
                                                 const int* __restrict__ f2f,
                                                 unsigned short* __restrict__ W16) {
    __shared__ float a_lds[FK];          // 4.8 KB
    __shared__ float c_lds[256 * 44];    // 45 KB (pad 40->44)

    const int i   = blockIdx.y;
    const int j0  = blockIdx.x * 256;
    const int tid = threadIdx.x;
    const int fi  = f2f[i];

    // stage v[i][:][:]
    for (int q = tid; q < FK; q += 256) a_lds[q] = v[(size_t)i * FK + q];
    // stage c rows: 256 rows x 10 float4, lanes 0-9 contiguous per row
    for (int q = tid; q < 2560; q += 256) {
        const int jl = q / 10, c4 = q % 10;
        *(float4*)&c_lds[jl * 44 + c4 * 4] =
            *(const float4*)&v[(size_t)(j0 + jl) * FK + fi * KDIM + c4 * 4];
    }
    __syncthreads();

    const int j  = j0 + tid;
    const int fj = f2f[j];
    const float4* a = (const float4*)&a_lds[fj * KDIM];
    const float4* c = (const float4*)&c_lds[tid * 44];
    float acc = 0.f;
#pragma unroll
    for (int q = 0; q < KDIM / 4; ++q) {
        float4 av = a[q], cv = c[q];
        acc = fmaf(av.x, cv.x, acc);
        acc = fmaf(av.y, cv.y, acc);
        acc = fmaf(av.z, cv.z, acc);
        acc = fmaf(av.w, cv.w, acc);
    }
    W16[(size_t)i * N_FEAT + j] = (i == j) ? (unsigned short)0 : bf16_rne(0.5f * acc);
}

// ---------------- Kernel 2: fused GEMM + quadratic-form epilogue ----------------
// grid: 512 blocks x 512 threads (8 waves). Wave w: wm=w&1 (32 rows),
// wn=w>>1 (32 cols of 128-col cb panel). Per-wave output 32x32 per cb.
// A-frags in registers (full K); Bs[2] 32KB halves staged with 4
// global_load_lds/thread/step, vmcnt(4) counted wait.
__global__ __launch_bounds__(512, 2) void ffm_fused(const float* __restrict__ X,
                                                    const unsigned short* __restrict__ W16,
                                                    const float* __restrict__ w1,
                                                    const float* __restrict__ bvec,
                                                    float* __restrict__ out) {
    __shared__ __align__(16) unsigned short As[BM * N_FEAT];    // 64 KB, full-K X tile
    __shared__ __align__(16) unsigned short Bs[2][128 * BK2];   // 2 x 32 KB, W16 dbuf
    __shared__ float part[4 * BM];                              // 1 KB

    const int tid  = threadIdx.x;
    const int lane = tid & 63;
    const int wave = tid >> 6;       // 0..7
    const int wm = wave & 1;
    const int wn = wave >> 1;        // 0..3
    const int quad = lane >> 4;
    const int l16  = lane & 15;
    const int aswz = l16 & 7;

    const size_t row0 = (size_t)blockIdx.x * BM;

    // Preload w1 fragments + bias: no VMEM inside the pipelined loop.
    float w1v[4][2];
#pragma unroll
    for (int cb = 0; cb < 4; ++cb)
#pragma unroll
        for (int ni = 0; ni < 2; ++ni)
            w1v[cb][ni] = w1[cb * 128 + wn * 32 + ni * 16 + l16];
    const float bias = bvec[0];

    // Stage 32KB W16 tile for step s (s=0..15) into Bs[s&1].
    // Bs row r (=W16 col within panel), 16 chunks of 16B, chunk c stored at c^(r&7).
    // Dest is wave-uniform base + lane*16 (r = wave*16+i*4+quad, cs = l16).
    auto stage = [&](int s) {
        const int col0 = (s >> 2) * 128;
        const int k0   = (s & 3) * BK2;
        unsigned short* dst = (unsigned short*)Bs[s & 1];
#pragma unroll
        for (int i = 0; i < 4; ++i) {
            const int r = wave * 16 + i * 4 + quad;   // 0..127
            async_copy16(W16 + (size_t)(col0 + r) * N_FEAT + k0 + ((l16 ^ (r & 7)) << 3),
                         dst + r * BK2 + l16 * 8);
        }
    };

    // ---- Prologue: issue tile-0 staging, then build As under it ----
    stage(0);
    {
        const float4* X4 = (const float4*)(X + row0 * N_FEAT);
#pragma unroll
        for (int u = 0; u < 8; ++u) {
            const int g  = u * 512 + tid;
            const int r  = g >> 6;          // 0..63
            const int cc = g & 63;          // 16B chunk in row
            float4 f0 = X4[r * 128 + cc * 2];
            float4 f1 = X4[r * 128 + cc * 2 + 1];
            union { unsigned short us[8]; short8 v; } pk;
            pk.us[0] = bf16_rne(f0.x);
            pk.us[1] = bf16_rne(f0.y);
            pk.us[2] = bf16_rne(f0.z);
            pk.us[3] = bf16_rne(f0.w);
            pk.us[4] = bf16_rne(f1.x);
            pk.us[5] = bf16_rne(f1.y);
            pk.us[6] = bf16_rne(f1.z);
            pk.us[7] = bf16_rne(f1.w);
            *(short8*)(As + r * N_FEAT + ((cc ^ (r & 7)) << 3)) = pk.v;
        }
    }
    asm volatile("s_waitcnt lgkmcnt(0)" ::: "memory");
    __builtin_amdgcn_s_barrier();
    FENCE();

    // ---- Hoist all A-fragments to registers: 2 mi x 16 k-chunks ----
    short8 areg[2][16];
#pragma unroll
    for (int ka = 0; ka < 16; ++ka)
#pragma unroll
        for (int mi = 0; mi < 2; ++mi) {
            const int ar = wm * 32 + mi * 16 + l16;   // ar&7 == aswz
            areg[mi][ka] = *(const short8*)(As + ar * N_FEAT + (((ka * 4 + quad) ^ aswz) << 3));
        }

    float rs[2][4];
#pragma unroll
    for (int mi = 0; mi < 2; ++mi)
#pragma unroll
        for (int reg = 0; reg < 4; ++reg) rs[mi][reg] = 0.f;

    f32x4 acc[2][2];
#pragma unroll
    for (int mi = 0; mi < 2; ++mi)
#pragma unroll
        for (int ni = 0; ni < 2; ++ni)
            acc[mi][ni] = (f32x4){0.f, 0.f, 0.f, 0.f};

#pragma unroll
    for (int cb = 0; cb < 4; ++cb) {
        const int col0 = cb * 128;
#pragma unroll
        for (int t = 0; t < 4; ++t) {
            const int s = cb * 4 + t;
            // Stage next tile (into buffer last read at s-1; safe past the
            // end-of-(s-1) barrier). Counted wait: stage(s) done, s+1 in flight.
            if (s < 15) {
                stage(s + 1);
                asm volatile("s_waitcnt vmcnt(4)" ::: "memory");
            } else {
                asm volatile("s_waitcnt vmcnt(0)" ::: "memory");
            }
            __builtin_amdgcn_s_barrier();   // all waves' cur-buf loads landed
            FENCE();

            const unsigned short* bs = (const unsigned short*)Bs[s & 1];
            __builtin_amdgcn_s_setprio(1);
#pragma unroll
            for (int kk = 0; kk < 4; ++kk) {
                const int ka = t * 4 + kk;                    // global K/32 chunk
                short8 b[2];
                const int swc = ((kk * 4 + quad) ^ aswz) << 3;
#pragma unroll
                for (int ni = 0; ni < 2; ++ni) {
                    const int br = wn * 32 + ni * 16 + l16;   // br&7 == aswz
                    b[ni] = *(const short8*)(bs + br * BK2 + swc);
                }
#pragma unroll
                for (int mi = 0; mi < 2; ++mi)
#pragma unroll
                    for (int ni = 0; ni < 2; ++ni)
                        acc[mi][ni] = __builtin_amdgcn_mfma_f32_16x16x32_bf16(
                            areg[mi][ka], b[ni], acc[mi][ni], 0, 0, 0);
            }
            __builtin_amdgcn_s_setprio(0);

            FENCE();
            __builtin_amdgcn_s_barrier();   // cur-buf reads done before next overwrite
            FENCE();
        }

        // Epilogue for this col-block: rs += x_hat * (y + w1), x_hat from As.
#pragma unroll
        for (int mi = 0; mi < 2; ++mi) {
#pragma unroll
            for (int ni = 0; ni < 2; ++ni) {
                const int gc = col0 + wn * 32 + ni * 16 + l16;   // elem idx in K
#pragma unroll
                for (int reg = 0; reg < 4; ++reg) {
                    const int row = wm * 32 + mi * 16 + quad * 4 + reg;
                    const int adr = row * N_FEAT + ((((gc >> 3) ^ (row & 7)) << 3) | (gc & 7));
                    const float xf = bf16_to_f(As[adr]);
                    rs[mi][reg] = fmaf(xf, acc[mi][ni][reg] + w1v[cb][ni], rs[mi][reg]);
                }
                acc[mi][ni] = (f32x4){0.f, 0.f, 0.f, 0.f};
            }
        }
    }

    // Reduce over l16, combine the 4 wn column-quarters, bias + sigmoid.
#pragma unroll
    for (int mi = 0; mi < 2; ++mi)
#pragma unroll
        for (int reg = 0; reg < 4; ++reg) {
            float r = rs[mi][reg];
#pragma unroll
            for (int off = 1; off < 16; off <<= 1)
                r += __shfl_xor(r, off, 16);
            if (l16 == 0)
                part[wn * BM + wm * 32 + mi * 16 + quad * 4 + reg] = r;
        }
    __syncthreads();

    if (tid < BM) {
        const float t = part[tid] + part[BM + tid] + part[2 * BM + tid] +
                        part[3 * BM + tid] + bias;
        out[row0 + tid] = 1.0f / (1.0f + expf(-t));
    }
}

extern "C" void kernel_launch(void* const* d_in, const int* in_sizes, int n_in,
                              void* d_out, int out_size, void* d_ws, size_t ws_size,
                              hipStream_t stream) {
    const float* X   = (const float*)d_in[0];   // 32768 x 512
    const float* w1  = (const float*)d_in[1];   // 512
    const float* b   = (const float*)d_in[2];   // 1
    const float* v   = (const float*)d_in[3];   // 512 x 30 x 40
    const int*   f2f = (const int*)d_in[4];     // 512
    float* out = (float*)d_out;                 // 32768

    unsigned short* W16 = (unsigned short*)d_ws;   // 512 KB scratch

    build_w16<<<dim3(2, N_FEAT), 256, 0, stream>>>(v, f2f, W16);
    ffm_fused<<<B_ROWS / BM, 512, 0, stream>>>(X, W16, w1, b, out);
}